// Round 13
// baseline (82.376 us; speedup 1.0000x reference)
//
#include <hip/hip_runtime.h>
#include <hip/hip_bf16.h>

#define B_ 2
#define N_ 2048
#define FIN 512
#define H_ 8
#define DH 64
#define HD 512 /* H_*DH */
#define SLOPE 0.2f

typedef __attribute__((ext_vector_type(8))) short short8;
typedef __attribute__((ext_vector_type(4))) float f32x4;
typedef unsigned short ushort_t;

__device__ __forceinline__ ushort_t hi_trunc(float x) {
  return (ushort_t)(__float_as_uint(x) >> 16);
}
__device__ __forceinline__ ushort_t lo_part(float x) {
  const float hf = __uint_as_float(__float_as_uint(x) & 0xFFFF0000u);
  const __hip_bfloat16 lb = __float2bfloat16(x - hf);
  return *(const ushort_t*)&lb;
}
__device__ __forceinline__ ushort_t bf16_rne(float x) {
  const __hip_bfloat16 b = __float2bfloat16(x);
  return *(const ushort_t*)&b;
}

// K1: g = f @ W via bf16 MFMA split precision (ah*bh + ah*bl + al*bh).
// fp32->bf16 hi/lo conversion fused into staging (regs -> swizzled ds_write).
// BM=128, BN=64, BK=64, 512 thr (8 waves), dbuf, load-early/write-late.
// Fused sl/sr epilogue (col tile == head). Grid (32, 8).  [R12, unchanged]
__global__ __launch_bounds__(512) void k_gemm_fused(
    const float* __restrict__ f, const float* __restrict__ W,
    const float* __restrict__ aw, float* __restrict__ C,
    float* __restrict__ sl, float* __restrict__ sr) {
  __shared__ ushort_t lA[2][2][128 * 64];  // [buf][hi/lo] 64KB
  __shared__ ushort_t lB[2][2][64 * 64];   // 32KB
  __shared__ float slp[2][128], srp[2][128];
  const int tid = threadIdx.x;
  const int lane = tid & 63;
  const int wave = tid >> 6;
  const int row0 = blockIdx.x * 128;
  const int col0 = blockIdx.y * 64;
  const int wm = (wave >> 1) * 32;
  const int wn = (wave & 1) * 32;
  const int ar = tid >> 2;             // A row 0..127
  const int aks = (tid & 3) * 16;      // A k-segment (elements)
  const int bn = tid & 63;             // B col (n) == lane -> coalesced
  const int bks = (tid >> 6) * 8;      // B k-segment
  f32x4 acc[2][2] = {};
  float fa[16];
  float fb[8];

#define LOADR(k0)                                                           \
  {                                                                         \
    const float* ap = f + (row0 + ar) * FIN + (k0) + aks;                   \
    _Pragma("unroll") for (int i = 0; i < 4; ++i) {                         \
      const float4 v = *(const float4*)(ap + i * 4);                        \
      fa[i * 4 + 0] = v.x; fa[i * 4 + 1] = v.y;                             \
      fa[i * 4 + 2] = v.z; fa[i * 4 + 3] = v.w;                             \
    }                                                                       \
    _Pragma("unroll") for (int j = 0; j < 8; ++j)                           \
      fb[j] = W[((k0) + bks + j) * HD + col0 + bn];                         \
  }

#define WRITELDS(buf)                                                       \
  {                                                                         \
    _Pragma("unroll") for (int c = 0; c < 2; ++c) {                         \
      short8 hv, lv;                                                        \
      _Pragma("unroll") for (int j = 0; j < 8; ++j) {                       \
        hv[j] = (short)hi_trunc(fa[c * 8 + j]);                             \
        lv[j] = (short)lo_part(fa[c * 8 + j]);                              \
      }                                                                     \
      const int kbA = ((tid & 3) << 5) + (c << 4);                          \
      const int offA = (ar * 128 + (kbA ^ ((ar & 7) << 4))) >> 1;           \
      *(short8*)&lA[buf][0][offA] = hv;                                     \
      *(short8*)&lA[buf][1][offA] = lv;                                     \
    }                                                                       \
    {                                                                       \
      short8 hv, lv;                                                        \
      _Pragma("unroll") for (int j = 0; j < 8; ++j) {                       \
        hv[j] = (short)hi_trunc(fb[j]);                                     \
        lv[j] = (short)lo_part(fb[j]);                                      \
      }                                                                     \
      const int kbB = bks << 1;                                             \
      const int offB = (bn * 128 + (kbB ^ ((bn & 7) << 4))) >> 1;           \
      *(short8*)&lB[buf][0][offB] = hv;                                     \
      *(short8*)&lB[buf][1][offB] = lv;                                     \
    }                                                                       \
  }

  LOADR(0);
  WRITELDS(0);
  __syncthreads();
  int cur = 0;
  for (int t = 0; t < 8; ++t) {
    if (t < 7) LOADR((t + 1) * 64);
#pragma unroll
    for (int kk = 0; kk < 2; ++kk) {
      short8 a_h[2], a_l[2], b_h[2], b_l[2];
      const int kbyte = kk * 64 + ((lane >> 4) << 4);
#pragma unroll
      for (int fm = 0; fm < 2; ++fm) {
        const int row = wm + fm * 16 + (lane & 15);
        const int off = (row * 128 + (kbyte ^ ((row & 7) << 4))) >> 1;
        a_h[fm] = *(const short8*)&lA[cur][0][off];
        a_l[fm] = *(const short8*)&lA[cur][1][off];
      }
#pragma unroll
      for (int fn = 0; fn < 2; ++fn) {
        const int nn = wn + fn * 16 + (lane & 15);
        const int off = (nn * 128 + (kbyte ^ ((nn & 7) << 4))) >> 1;
        b_h[fn] = *(const short8*)&lB[cur][0][off];
        b_l[fn] = *(const short8*)&lB[cur][1][off];
      }
#pragma unroll
      for (int fm = 0; fm < 2; ++fm)
#pragma unroll
        for (int fn = 0; fn < 2; ++fn) {
          acc[fm][fn] = __builtin_amdgcn_mfma_f32_16x16x32_bf16(
              a_h[fm], b_h[fn], acc[fm][fn], 0, 0, 0);
          acc[fm][fn] = __builtin_amdgcn_mfma_f32_16x16x32_bf16(
              a_h[fm], b_l[fn], acc[fm][fn], 0, 0, 0);
          acc[fm][fn] = __builtin_amdgcn_mfma_f32_16x16x32_bf16(
              a_l[fm], b_h[fn], acc[fm][fn], 0, 0, 0);
        }
    }
    if (t < 7) WRITELDS(cur ^ 1);
    __syncthreads();
    cur ^= 1;
  }
#undef LOADR
#undef WRITELDS

#pragma unroll
  for (int fm = 0; fm < 2; ++fm)
#pragma unroll
    for (int fn = 0; fn < 2; ++fn)
#pragma unroll
      for (int r = 0; r < 4; ++r) {
        const int row = row0 + wm + fm * 16 + ((lane >> 4) << 2) + r;
        const int col = col0 + wn + fn * 16 + (lane & 15);
        C[row * HD + col] = acc[fm][fn][r];
      }

  const float al0 = aw[wn + (lane & 15)];
  const float al1 = aw[wn + 16 + (lane & 15)];
  const float ar0 = aw[DH + wn + (lane & 15)];
  const float ar1 = aw[DH + wn + 16 + (lane & 15)];
#pragma unroll
  for (int fm = 0; fm < 2; ++fm)
#pragma unroll
    for (int r = 0; r < 4; ++r) {
      float vsl = acc[fm][0][r] * al0 + acc[fm][1][r] * al1;
      float vsr = acc[fm][0][r] * ar0 + acc[fm][1][r] * ar1;
#pragma unroll
      for (int off = 1; off < 16; off <<= 1) {
        vsl += __shfl_xor(vsl, off, 64);
        vsr += __shfl_xor(vsr, off, 64);
      }
      if ((lane & 15) == 0) {
        const int rr = wm + fm * 16 + ((lane >> 4) << 2) + r;
        slp[wn >> 5][rr] = vsl;
        srp[wn >> 5][rr] = vsr;
      }
    }
  __syncthreads();
  if (tid < 128) {
    const int grow = row0 + tid;
    const int b = grow >> 11, n = grow & (N_ - 1);
    const int h = blockIdx.y;
    sl[(b * H_ + h) * N_ + n] = slp[0][tid] + slp[1][tid];
    sr[(b * H_ + h) * N_ + n] = srp[0][tid] + srp[1][tid];
  }
}

// K2: flash-style attention. e[i][j] = lrelu(sl_i + sr_j) computed in-register
// (rank-1 score structure -> no QK^T matmul). Online softmax over 32 j-tiles
// of 64; PV via mfma_16x16x32_bf16 with g split hi/lo (exact B operand).
// Grid (16 i-tiles, 16 bh) x 512 thr (8 waves x 16 rows). g-tile in swizzled
// LDS [d][j] (byte ^= (d&7)<<4): conflict-free b128 writes AND reads.
__global__ __launch_bounds__(512) void k_attn(const float* __restrict__ g,
                                              const float* __restrict__ sl,
                                              const float* __restrict__ sr,
                                              float* __restrict__ out) {
  __shared__ ushort_t ghi[2][64 * 64];  // 16KB
  __shared__ ushort_t glo[2][64 * 64];  // 16KB
  const int tid = threadIdx.x;
  const int lane = tid & 63;
  const int wave = tid >> 6;
  const int bh = blockIdx.y;
  const int b = bh >> 3, h = bh & 7;
  const int i0 = blockIdx.x * 128 + wave * 16;  // wave's first output row
  const int row_l = lane & 15;                  // A-frag row / B-frag col
  const int kg = lane >> 4;                     // k-group 0..3
  const int sd = tid >> 3;                      // staging d 0..63
  const int sj = (tid & 7) * 8;                 // staging j0
  const float sli = sl[bh * N_ + i0 + row_l];
  const float* gbase = g + (b * N_) * HD + h * DH;

  float m = -1e30f, Z = 0.f;
  f32x4 O[4] = {};
  float fa[8];

#define ALOAD(jb)                                                           \
  _Pragma("unroll") for (int u = 0; u < 8; ++u)                             \
      fa[u] = gbase[((jb) + sj + u) * HD + sd];

#define AWRITE(buf)                                                         \
  {                                                                         \
    short8 hv, lv;                                                          \
    _Pragma("unroll") for (int u = 0; u < 8; ++u) {                         \
      hv[u] = (short)hi_trunc(fa[u]);                                       \
      lv[u] = (short)lo_part(fa[u]);                                        \
    }                                                                       \
    const int idx = sd * 64 + (sj ^ ((sd & 7) << 3));                       \
    *(short8*)&ghi[buf][idx] = hv;                                          \
    *(short8*)&glo[buf][idx] = lv;                                          \
  }

  ALOAD(0);
  AWRITE(0);
  __syncthreads();
  int cur = 0;
  for (int t = 0; t < 32; ++t) {
    const int jb = t * 64;
    if (t < 31) ALOAD(jb + 64);
    // scores for this wave's 16 rows x 64 j (16 per lane)
    float e[16];
    float lmax = -1e30f;
#pragma unroll
    for (int kk = 0; kk < 2; ++kk) {
      const int jo = bh * N_ + jb + kk * 32 + kg * 8;
      const float4 s0 = *(const float4*)&sr[jo];
      const float4 s1 = *(const float4*)&sr[jo + 4];
      const float svv[8] = {s0.x, s0.y, s0.z, s0.w, s1.x, s1.y, s1.z, s1.w};
#pragma unroll
      for (int u = 0; u < 8; ++u) {
        float x = sli + svv[u];
        x = x >= 0.f ? x : SLOPE * x;
        e[kk * 8 + u] = x;
        lmax = fmaxf(lmax, x);
      }
    }
    lmax = fmaxf(lmax, __shfl_xor(lmax, 16, 64));
    lmax = fmaxf(lmax, __shfl_xor(lmax, 32, 64));  // row-max (4 lanes share)
    const float mnew = fmaxf(m, lmax);
    const float scale = __expf(m - mnew);  // per row_l
    m = mnew;
    Z *= scale;
    // rescale O: scale indexed by C-frag row (kg*4+rr)
    float sc[4];
#pragma unroll
    for (int rr = 0; rr < 4; ++rr) sc[rr] = __shfl(scale, kg * 4 + rr, 64);
#pragma unroll
    for (int gg = 0; gg < 4; ++gg)
#pragma unroll
      for (int rr = 0; rr < 4; ++rr) O[gg][rr] *= sc[rr];
    // P (bf16 RNE) + Z accumulation
    short8 a[2];
    float zadd = 0.f;
#pragma unroll
    for (int kk = 0; kk < 2; ++kk)
#pragma unroll
      for (int u = 0; u < 8; ++u) {
        const float p = __expf(e[kk * 8 + u] - mnew);
        zadd += p;
        a[kk][u] = (short)bf16_rne(p);
      }
    zadd += __shfl_xor(zadd, 16, 64);
    zadd += __shfl_xor(zadd, 32, 64);
    Z += zadd;
    // PV: B-frags from swizzled LDS, g split hi/lo
#pragma unroll
    for (int gg = 0; gg < 4; ++gg) {
      const int d = gg * 16 + row_l;
#pragma unroll
      for (int kk = 0; kk < 2; ++kk) {
        const int j0r = kk * 32 + kg * 8;
        const int idx = d * 64 + (j0r ^ ((d & 7) << 3));
        const short8 b_h = *(const short8*)&ghi[cur][idx];
        const short8 b_l = *(const short8*)&glo[cur][idx];
        O[gg] = __builtin_amdgcn_mfma_f32_16x16x32_bf16(a[kk], b_h, O[gg], 0, 0, 0);
        O[gg] = __builtin_amdgcn_mfma_f32_16x16x32_bf16(a[kk], b_l, O[gg], 0, 0, 0);
      }
    }
    if (t < 31) AWRITE(cur ^ 1);
    __syncthreads();
    cur ^= 1;
  }
#undef ALOAD
#undef AWRITE
  // epilogue: divide by Z (per C-frag row) and store
  float zr[4];
#pragma unroll
  for (int rr = 0; rr < 4; ++rr) zr[rr] = __shfl(Z, kg * 4 + rr, 64);
#pragma unroll
  for (int gg = 0; gg < 4; ++gg)
#pragma unroll
    for (int rr = 0; rr < 4; ++rr) {
      const int row = i0 + kg * 4 + rr;
      const int col = h * DH + gg * 16 + row_l;
      out[(b * N_ + row) * HD + col] = O[gg][rr] / zr[rr];
    }
}

extern "C" void kernel_launch(void* const* d_in, const int* in_sizes, int n_in,
                              void* d_out, int out_size, void* d_ws, size_t ws_size,
                              hipStream_t stream) {
  const float* f = (const float*)d_in[0];
  // d_in[1] = adj_mat (all ones, unused by reference math)
  const float* W = (const float*)d_in[2];
  const float* aw = (const float*)d_in[3];
  float* out = (float*)d_out;

  float* g = (float*)d_ws;            // 2*2048*512 fp32
  float* sl = g + B_ * N_ * HD;       // [bh][n]
  float* sr = sl + B_ * N_ * H_;

  hipLaunchKernelGGL(k_gemm_fused, dim3((B_ * N_) / 128, HD / 64), dim3(512), 0, stream,
                     f, W, aw, g, sl, sr);
  hipLaunchKernelGGL(k_attn, dim3(N_ / 128, B_ * H_), dim3(512), 0, stream,
                     g, sl, sr, out);
}

// Round 14
// 68.492 us; speedup vs baseline: 1.2027x; 1.2027x over previous
//
#include <hip/hip_runtime.h>
#include <hip/hip_bf16.h>

#define B_ 2
#define N_ 2048
#define FIN 512
#define H_ 8
#define DH 64
#define HD 512 /* H_*DH */
#define SLOPE 0.2f

typedef __attribute__((ext_vector_type(8))) short short8;
typedef __attribute__((ext_vector_type(4))) float f32x4;
typedef unsigned short ushort_t;

__device__ __forceinline__ ushort_t hi_trunc(float x) {
  return (ushort_t)(__float_as_uint(x) >> 16);
}
__device__ __forceinline__ ushort_t lo_part(float x) {
  const float hf = __uint_as_float(__float_as_uint(x) & 0xFFFF0000u);
  const __hip_bfloat16 lb = __float2bfloat16(x - hf);
  return *(const ushort_t*)&lb;
}
__device__ __forceinline__ ushort_t bf16_rne(float x) {
  const __hip_bfloat16 b = __float2bfloat16(x);
  return *(const ushort_t*)&b;
}

// K1: g = f @ W via bf16 MFMA split precision. BM=128, BN=64, BK=64, 512 thr.
// Epilogue: (a) LDS-bounce TRANSPOSE of the head-tile -> gThi/gTlo[bh][d][n]
// (bf16 hi/lo, coalesced row stores) for the attn kernel; (b) fused sl/sr.
__global__ __launch_bounds__(512) void k_gemm_fused(
    const float* __restrict__ f, const float* __restrict__ W,
    const float* __restrict__ aw, ushort_t* __restrict__ gThi,
    ushort_t* __restrict__ gTlo, float* __restrict__ sl,
    float* __restrict__ sr) {
  __shared__ ushort_t lA[2][2][128 * 64];  // 64KB; reused as fp32 T[64][132]
  __shared__ ushort_t lB[2][2][64 * 64];   // 32KB
  __shared__ float slp[2][128], srp[2][128];
  const int tid = threadIdx.x;
  const int lane = tid & 63;
  const int wave = tid >> 6;
  const int row0 = blockIdx.x * 128;
  const int col0 = blockIdx.y * 64;
  const int wm = (wave >> 1) * 32;
  const int wn = (wave & 1) * 32;
  const int ar = tid >> 2;
  const int aks = (tid & 3) * 16;
  const int bn = tid & 63;
  const int bks = (tid >> 6) * 8;
  f32x4 acc[2][2] = {};
  float fa[16];
  float fb[8];

#define LOADR(k0)                                                           \
  {                                                                         \
    const float* ap = f + (row0 + ar) * FIN + (k0) + aks;                   \
    _Pragma("unroll") for (int i = 0; i < 4; ++i) {                         \
      const float4 v = *(const float4*)(ap + i * 4);                        \
      fa[i * 4 + 0] = v.x; fa[i * 4 + 1] = v.y;                             \
      fa[i * 4 + 2] = v.z; fa[i * 4 + 3] = v.w;                             \
    }                                                                       \
    _Pragma("unroll") for (int j = 0; j < 8; ++j)                           \
      fb[j] = W[((k0) + bks + j) * HD + col0 + bn];                         \
  }

#define WRITELDS(buf)                                                       \
  {                                                                         \
    _Pragma("unroll") for (int c = 0; c < 2; ++c) {                         \
      short8 hv, lv;                                                        \
      _Pragma("unroll") for (int j = 0; j < 8; ++j) {                       \
        hv[j] = (short)hi_trunc(fa[c * 8 + j]);                             \
        lv[j] = (short)lo_part(fa[c * 8 + j]);                              \
      }                                                                     \
      const int kbA = ((tid & 3) << 5) + (c << 4);                          \
      const int offA = (ar * 128 + (kbA ^ ((ar & 7) << 4))) >> 1;           \
      *(short8*)&lA[buf][0][offA] = hv;                                     \
      *(short8*)&lA[buf][1][offA] = lv;                                     \
    }                                                                       \
    {                                                                       \
      short8 hv, lv;                                                        \
      _Pragma("unroll") for (int j = 0; j < 8; ++j) {                       \
        hv[j] = (short)hi_trunc(fb[j]);                                     \
        lv[j] = (short)lo_part(fb[j]);                                      \
      }                                                                     \
      const int kbB = bks << 1;                                             \
      const int offB = (bn * 128 + (kbB ^ ((bn & 7) << 4))) >> 1;           \
      *(short8*)&lB[buf][0][offB] = hv;                                     \
      *(short8*)&lB[buf][1][offB] = lv;                                     \
    }                                                                       \
  }

  LOADR(0);
  WRITELDS(0);
  __syncthreads();
  int cur = 0;
  for (int t = 0; t < 8; ++t) {
    if (t < 7) LOADR((t + 1) * 64);
#pragma unroll
    for (int kk = 0; kk < 2; ++kk) {
      short8 a_h[2], a_l[2], b_h[2], b_l[2];
      const int kbyte = kk * 64 + ((lane >> 4) << 4);
#pragma unroll
      for (int fm = 0; fm < 2; ++fm) {
        const int row = wm + fm * 16 + (lane & 15);
        const int off = (row * 128 + (kbyte ^ ((row & 7) << 4))) >> 1;
        a_h[fm] = *(const short8*)&lA[cur][0][off];
        a_l[fm] = *(const short8*)&lA[cur][1][off];
      }
#pragma unroll
      for (int fn = 0; fn < 2; ++fn) {
        const int nn = wn + fn * 16 + (lane & 15);
        const int off = (nn * 128 + (kbyte ^ ((nn & 7) << 4))) >> 1;
        b_h[fn] = *(const short8*)&lB[cur][0][off];
        b_l[fn] = *(const short8*)&lB[cur][1][off];
      }
#pragma unroll
      for (int fm = 0; fm < 2; ++fm)
#pragma unroll
        for (int fn = 0; fn < 2; ++fn) {
          acc[fm][fn] = __builtin_amdgcn_mfma_f32_16x16x32_bf16(
              a_h[fm], b_h[fn], acc[fm][fn], 0, 0, 0);
          acc[fm][fn] = __builtin_amdgcn_mfma_f32_16x16x32_bf16(
              a_h[fm], b_l[fn], acc[fm][fn], 0, 0, 0);
          acc[fm][fn] = __builtin_amdgcn_mfma_f32_16x16x32_bf16(
              a_l[fm], b_h[fn], acc[fm][fn], 0, 0, 0);
        }
    }
    if (t < 7) WRITELDS(cur ^ 1);
    __syncthreads();
    cur ^= 1;
  }
#undef LOADR
#undef WRITELDS

  // ---- epilogue A: transpose head-tile via LDS, store bf16 hi/lo gT ----
  float* T = (float*)lA;  // [64 cols][132 rows-padded] fp32 = 33.8KB
#pragma unroll
  for (int fm = 0; fm < 2; ++fm)
#pragma unroll
    for (int fn = 0; fn < 2; ++fn)
#pragma unroll
      for (int r = 0; r < 4; ++r) {
        const int col = wn + fn * 16 + (lane & 15);
        const int rl = wm + fm * 16 + ((lane >> 4) << 2) + r;
        T[col * 132 + rl] = acc[fm][fn][r];
      }
  __syncthreads();
  {
    const int b = row0 >> 11;
    const int n0 = row0 & (N_ - 1);
    const int d = tid >> 3;
    const int nc = (tid & 7) * 16;
    const size_t gb = ((size_t)((b * H_ + blockIdx.y) * 64 + d)) * N_ + n0 + nc;
#pragma unroll
    for (int half = 0; half < 2; ++half) {
      short8 hv, lv;
#pragma unroll
      for (int u = 0; u < 8; ++u) {
        const float x = T[d * 132 + nc + half * 8 + u];
        hv[u] = (short)hi_trunc(x);
        lv[u] = (short)lo_part(x);
      }
      *(short8*)&gThi[gb + half * 8] = hv;
      *(short8*)&gTlo[gb + half * 8] = lv;
    }
  }

  // ---- epilogue B: fused sl/sr ----
  const float al0 = aw[wn + (lane & 15)];
  const float al1 = aw[wn + 16 + (lane & 15)];
  const float ar0 = aw[DH + wn + (lane & 15)];
  const float ar1 = aw[DH + wn + 16 + (lane & 15)];
#pragma unroll
  for (int fm = 0; fm < 2; ++fm)
#pragma unroll
    for (int r = 0; r < 4; ++r) {
      float vsl = acc[fm][0][r] * al0 + acc[fm][1][r] * al1;
      float vsr = acc[fm][0][r] * ar0 + acc[fm][1][r] * ar1;
#pragma unroll
      for (int off = 1; off < 16; off <<= 1) {
        vsl += __shfl_xor(vsl, off, 64);
        vsr += __shfl_xor(vsr, off, 64);
      }
      if ((lane & 15) == 0) {
        const int rr = wm + fm * 16 + ((lane >> 4) << 2) + r;
        slp[wn >> 5][rr] = vsl;
        srp[wn >> 5][rr] = vsr;
      }
    }
  __syncthreads();
  if (tid < 128) {
    const int grow = row0 + tid;
    const int b = grow >> 11, n = grow & (N_ - 1);
    const int h = blockIdx.y;
    sl[(b * H_ + h) * N_ + n] = slp[0][tid] + slp[1][tid];
    sr[(b * H_ + h) * N_ + n] = srp[0][tid] + srp[1][tid];
  }
}

// K2: flash attention with rank-1 scores. Grid (32 i-tiles, 16 bh) x 256 thr
// (4 waves x 16 rows). gT pre-split/pre-transposed: staging = coalesced
// ushort8 loads + swizzled ds_write_b128 (no conversion, no gather).
__global__ __launch_bounds__(256) void k_attn(const ushort_t* __restrict__ gThi,
                                              const ushort_t* __restrict__ gTlo,
                                              const float* __restrict__ sl,
                                              const float* __restrict__ sr,
                                              float* __restrict__ out) {
  __shared__ ushort_t ghi[2][64 * 64];  // 8KB each buf
  __shared__ ushort_t glo[2][64 * 64];
  const int tid = threadIdx.x;
  const int lane = tid & 63;
  const int wave = tid >> 6;
  const int bh = blockIdx.y;
  const int b = bh >> 3, h = bh & 7;
  const int i0 = blockIdx.x * 64 + wave * 16;
  const int row_l = lane & 15;
  const int kg = lane >> 4;
  const int sd = tid >> 2;              // staging d 0..63
  const int sj = (tid & 3) * 16;        // staging j0 (16 ushorts = 2 x short8)
  const float sli = sl[bh * N_ + i0 + row_l];
  const size_t gbase = ((size_t)bh) * 64 * N_;

  float m = -1e30f, Z = 0.f;
  f32x4 O[4] = {};
  short8 sh[2], slo[2];

#define ALOAD(jb)                                                           \
  {                                                                         \
    const size_t src = gbase + (size_t)sd * N_ + (jb) + sj;                 \
    sh[0] = *(const short8*)&gThi[src];                                     \
    sh[1] = *(const short8*)&gThi[src + 8];                                 \
    slo[0] = *(const short8*)&gTlo[src];                                    \
    slo[1] = *(const short8*)&gTlo[src + 8];                                \
  }

#define AWRITE(buf)                                                         \
  {                                                                         \
    const int base_ = sd * 64;                                              \
    const int sw_ = (sd & 7) << 3;                                          \
    *(short8*)&ghi[buf][base_ + (sj ^ sw_)] = sh[0];                        \
    *(short8*)&ghi[buf][base_ + ((sj + 8) ^ sw_)] = sh[1];                  \
    *(short8*)&glo[buf][base_ + (sj ^ sw_)] = slo[0];                       \
    *(short8*)&glo[buf][base_ + ((sj + 8) ^ sw_)] = slo[1];                 \
  }

  ALOAD(0);
  AWRITE(0);
  __syncthreads();
  int cur = 0;
  for (int t = 0; t < 32; ++t) {
    const int jb = t * 64;
    if (t < 31) ALOAD(jb + 64);
    // scores: 16 rows x 64 j; this lane: i = row_l, j = kk*32 + kg*8 + u
    float e[16];
    float lmax = -1e30f;
#pragma unroll
    for (int kk = 0; kk < 2; ++kk) {
      const int jo = bh * N_ + jb + kk * 32 + kg * 8;
      const float4 s0 = *(const float4*)&sr[jo];
      const float4 s1 = *(const float4*)&sr[jo + 4];
      const float svv[8] = {s0.x, s0.y, s0.z, s0.w, s1.x, s1.y, s1.z, s1.w};
#pragma unroll
      for (int u = 0; u < 8; ++u) {
        float x = sli + svv[u];
        x = x >= 0.f ? x : SLOPE * x;
        e[kk * 8 + u] = x;
        lmax = fmaxf(lmax, x);
      }
    }
    lmax = fmaxf(lmax, __shfl_xor(lmax, 16, 64));
    lmax = fmaxf(lmax, __shfl_xor(lmax, 32, 64));
    const float mnew = fmaxf(m, lmax);
    const float scale = __expf(m - mnew);
    m = mnew;
    Z *= scale;
    float sc[4];
#pragma unroll
    for (int rr = 0; rr < 4; ++rr) sc[rr] = __shfl(scale, kg * 4 + rr, 64);
#pragma unroll
    for (int gg = 0; gg < 4; ++gg)
#pragma unroll
      for (int rr = 0; rr < 4; ++rr) O[gg][rr] *= sc[rr];
    short8 a[2];
    float zadd = 0.f;
#pragma unroll
    for (int kk = 0; kk < 2; ++kk)
#pragma unroll
      for (int u = 0; u < 8; ++u) {
        const float p = __expf(e[kk * 8 + u] - mnew);
        zadd += p;
        a[kk][u] = (short)bf16_rne(p);
      }
    zadd += __shfl_xor(zadd, 16, 64);
    zadd += __shfl_xor(zadd, 32, 64);
    Z += zadd;
#pragma unroll
    for (int gg = 0; gg < 4; ++gg) {
      const int d = gg * 16 + row_l;
#pragma unroll
      for (int kk = 0; kk < 2; ++kk) {
        const int j0r = kk * 32 + kg * 8;
        const int idx = d * 64 + (j0r ^ ((d & 7) << 3));
        const short8 b_h = *(const short8*)&ghi[cur][idx];
        const short8 b_l = *(const short8*)&glo[cur][idx];
        O[gg] = __builtin_amdgcn_mfma_f32_16x16x32_bf16(a[kk], b_h, O[gg], 0, 0, 0);
        O[gg] = __builtin_amdgcn_mfma_f32_16x16x32_bf16(a[kk], b_l, O[gg], 0, 0, 0);
      }
    }
    if (t < 31) AWRITE(cur ^ 1);
    __syncthreads();
    cur ^= 1;
  }
#undef ALOAD
#undef AWRITE
  float zr[4];
#pragma unroll
  for (int rr = 0; rr < 4; ++rr) zr[rr] = __shfl(Z, kg * 4 + rr, 64);
#pragma unroll
  for (int gg = 0; gg < 4; ++gg)
#pragma unroll
    for (int rr = 0; rr < 4; ++rr) {
      const int row = i0 + kg * 4 + rr;
      const int col = h * DH + gg * 16 + row_l;
      out[(b * N_ + row) * HD + col] = O[gg][rr] / zr[rr];
    }
}

extern "C" void kernel_launch(void* const* d_in, const int* in_sizes, int n_in,
                              void* d_out, int out_size, void* d_ws, size_t ws_size,
                              hipStream_t stream) {
  const float* f = (const float*)d_in[0];
  // d_in[1] = adj_mat (all ones, unused by reference math)
  const float* W = (const float*)d_in[2];
  const float* aw = (const float*)d_in[3];
  float* out = (float*)d_out;

  ushort_t* gThi = (ushort_t*)d_ws;          // [16 bh][64 d][2048 n] bf16 hi
  ushort_t* gTlo = gThi + 16 * 64 * N_;      // lo
  float* sl = (float*)(gTlo + 16 * 64 * N_); // [bh][n]
  float* sr = sl + B_ * N_ * H_;

  hipLaunchKernelGGL(k_gemm_fused, dim3((B_ * N_) / 128, HD / 64), dim3(512), 0, stream,
                     f, W, aw, gThi, gTlo, sl, sr);
  hipLaunchKernelGGL(k_attn, dim3(N_ / 64, B_ * H_), dim3(256), 0, stream,
                     gThi, gTlo, sl, sr, out);
}

// Round 15
// 61.248 us; speedup vs baseline: 1.3449x; 1.1183x over previous
//
#include <hip/hip_runtime.h>
#include <hip/hip_bf16.h>

#define B_ 2
#define N_ 2048
#define FIN 512
#define H_ 8
#define DH 64
#define HD 512 /* H_*DH */
#define SLOPE 0.2f
#define LOG2E 1.44269504088896340736f

typedef __attribute__((ext_vector_type(8))) short short8;
typedef __attribute__((ext_vector_type(4))) float f32x4;
typedef unsigned short ushort_t;

__device__ __forceinline__ ushort_t hi_trunc(float x) {
  return (ushort_t)(__float_as_uint(x) >> 16);
}
__device__ __forceinline__ ushort_t lo_part(float x) {
  const float hf = __uint_as_float(__float_as_uint(x) & 0xFFFF0000u);
  const __hip_bfloat16 lb = __float2bfloat16(x - hf);
  return *(const ushort_t*)&lb;
}
__device__ __forceinline__ ushort_t bf16_rne(float x) {
  const __hip_bfloat16 b = __float2bfloat16(x);
  return *(const ushort_t*)&b;
}

// K1: g = f @ W via bf16 MFMA split precision. BM=128, BN=64, BK=64, 512 thr.
// Epilogue: (a) LDS-bounce TRANSPOSE -> gThi/gTlo[bh][d][n] (bf16 hi/lo,
// coalesced row stores); (b) fused sl/sr.  [R14, unchanged — passed]
__global__ __launch_bounds__(512) void k_gemm_fused(
    const float* __restrict__ f, const float* __restrict__ W,
    const float* __restrict__ aw, ushort_t* __restrict__ gThi,
    ushort_t* __restrict__ gTlo, float* __restrict__ sl,
    float* __restrict__ sr) {
  __shared__ ushort_t lA[2][2][128 * 64];  // 64KB; reused as fp32 T[64][132]
  __shared__ ushort_t lB[2][2][64 * 64];   // 32KB
  __shared__ float slp[2][128], srp[2][128];
  const int tid = threadIdx.x;
  const int lane = tid & 63;
  const int wave = tid >> 6;
  const int row0 = blockIdx.x * 128;
  const int col0 = blockIdx.y * 64;
  const int wm = (wave >> 1) * 32;
  const int wn = (wave & 1) * 32;
  const int ar = tid >> 2;
  const int aks = (tid & 3) * 16;
  const int bn = tid & 63;
  const int bks = (tid >> 6) * 8;
  f32x4 acc[2][2] = {};
  float fa[16];
  float fb[8];

#define LOADR(k0)                                                           \
  {                                                                         \
    const float* ap = f + (row0 + ar) * FIN + (k0) + aks;                   \
    _Pragma("unroll") for (int i = 0; i < 4; ++i) {                         \
      const float4 v = *(const float4*)(ap + i * 4);                        \
      fa[i * 4 + 0] = v.x; fa[i * 4 + 1] = v.y;                             \
      fa[i * 4 + 2] = v.z; fa[i * 4 + 3] = v.w;                             \
    }                                                                       \
    _Pragma("unroll") for (int j = 0; j < 8; ++j)                           \
      fb[j] = W[((k0) + bks + j) * HD + col0 + bn];                         \
  }

#define WRITELDS(buf)                                                       \
  {                                                                         \
    _Pragma("unroll") for (int c = 0; c < 2; ++c) {                         \
      short8 hv, lv;                                                        \
      _Pragma("unroll") for (int j = 0; j < 8; ++j) {                       \
        hv[j] = (short)hi_trunc(fa[c * 8 + j]);                             \
        lv[j] = (short)lo_part(fa[c * 8 + j]);                              \
      }                                                                     \
      const int kbA = ((tid & 3) << 5) + (c << 4);                          \
      const int offA = (ar * 128 + (kbA ^ ((ar & 7) << 4))) >> 1;           \
      *(short8*)&lA[buf][0][offA] = hv;                                     \
      *(short8*)&lA[buf][1][offA] = lv;                                     \
    }                                                                       \
    {                                                                       \
      short8 hv, lv;                                                        \
      _Pragma("unroll") for (int j = 0; j < 8; ++j) {                       \
        hv[j] = (short)hi_trunc(fb[j]);                                     \
        lv[j] = (short)lo_part(fb[j]);                                      \
      }                                                                     \
      const int kbB = bks << 1;                                             \
      const int offB = (bn * 128 + (kbB ^ ((bn & 7) << 4))) >> 1;           \
      *(short8*)&lB[buf][0][offB] = hv;                                     \
      *(short8*)&lB[buf][1][offB] = lv;                                     \
    }                                                                       \
  }

  LOADR(0);
  WRITELDS(0);
  __syncthreads();
  int cur = 0;
  for (int t = 0; t < 8; ++t) {
    if (t < 7) LOADR((t + 1) * 64);
#pragma unroll
    for (int kk = 0; kk < 2; ++kk) {
      short8 a_h[2], a_l[2], b_h[2], b_l[2];
      const int kbyte = kk * 64 + ((lane >> 4) << 4);
#pragma unroll
      for (int fm = 0; fm < 2; ++fm) {
        const int row = wm + fm * 16 + (lane & 15);
        const int off = (row * 128 + (kbyte ^ ((row & 7) << 4))) >> 1;
        a_h[fm] = *(const short8*)&lA[cur][0][off];
        a_l[fm] = *(const short8*)&lA[cur][1][off];
      }
#pragma unroll
      for (int fn = 0; fn < 2; ++fn) {
        const int nn = wn + fn * 16 + (lane & 15);
        const int off = (nn * 128 + (kbyte ^ ((nn & 7) << 4))) >> 1;
        b_h[fn] = *(const short8*)&lB[cur][0][off];
        b_l[fn] = *(const short8*)&lB[cur][1][off];
      }
#pragma unroll
      for (int fm = 0; fm < 2; ++fm)
#pragma unroll
        for (int fn = 0; fn < 2; ++fn) {
          acc[fm][fn] = __builtin_amdgcn_mfma_f32_16x16x32_bf16(
              a_h[fm], b_h[fn], acc[fm][fn], 0, 0, 0);
          acc[fm][fn] = __builtin_amdgcn_mfma_f32_16x16x32_bf16(
              a_h[fm], b_l[fn], acc[fm][fn], 0, 0, 0);
          acc[fm][fn] = __builtin_amdgcn_mfma_f32_16x16x32_bf16(
              a_l[fm], b_h[fn], acc[fm][fn], 0, 0, 0);
        }
    }
    if (t < 7) WRITELDS(cur ^ 1);
    __syncthreads();
    cur ^= 1;
  }
#undef LOADR
#undef WRITELDS

  // ---- epilogue A: transpose head-tile via LDS, store bf16 hi/lo gT ----
  float* T = (float*)lA;  // [64 cols][132 rows-padded]
#pragma unroll
  for (int fm = 0; fm < 2; ++fm)
#pragma unroll
    for (int fn = 0; fn < 2; ++fn)
#pragma unroll
      for (int r = 0; r < 4; ++r) {
        const int col = wn + fn * 16 + (lane & 15);
        const int rl = wm + fm * 16 + ((lane >> 4) << 2) + r;
        T[col * 132 + rl] = acc[fm][fn][r];
      }
  __syncthreads();
  {
    const int b = row0 >> 11;
    const int n0 = row0 & (N_ - 1);
    const int d = tid >> 3;
    const int nc = (tid & 7) * 16;
    const size_t gb = ((size_t)((b * H_ + blockIdx.y) * 64 + d)) * N_ + n0 + nc;
#pragma unroll
    for (int half = 0; half < 2; ++half) {
      short8 hv, lv;
#pragma unroll
      for (int u = 0; u < 8; ++u) {
        const float x = T[d * 132 + nc + half * 8 + u];
        hv[u] = (short)hi_trunc(x);
        lv[u] = (short)lo_part(x);
      }
      *(short8*)&gThi[gb + half * 8] = hv;
      *(short8*)&gTlo[gb + half * 8] = lv;
    }
  }

  // ---- epilogue B: fused sl/sr ----
  const float al0 = aw[wn + (lane & 15)];
  const float al1 = aw[wn + 16 + (lane & 15)];
  const float ar0 = aw[DH + wn + (lane & 15)];
  const float ar1 = aw[DH + wn + 16 + (lane & 15)];
#pragma unroll
  for (int fm = 0; fm < 2; ++fm)
#pragma unroll
    for (int r = 0; r < 4; ++r) {
      float vsl = acc[fm][0][r] * al0 + acc[fm][1][r] * al1;
      float vsr = acc[fm][0][r] * ar0 + acc[fm][1][r] * ar1;
#pragma unroll
      for (int off = 1; off < 16; off <<= 1) {
        vsl += __shfl_xor(vsl, off, 64);
        vsr += __shfl_xor(vsr, off, 64);
      }
      if ((lane & 15) == 0) {
        const int rr = wm + fm * 16 + ((lane >> 4) << 2) + r;
        slp[wn >> 5][rr] = vsl;
        srp[wn >> 5][rr] = vsr;
      }
    }
  __syncthreads();
  if (tid < 128) {
    const int grow = row0 + tid;
    const int b = grow >> 11, n = grow & (N_ - 1);
    const int h = blockIdx.y;
    sl[(b * H_ + h) * N_ + n] = slp[0][tid] + slp[1][tid];
    sr[(b * H_ + h) * N_ + n] = srp[0][tid] + srp[1][tid];
  }
}

// K2: flash attention, rank-1 scores, NO online softmax: row max is exactly
// M_i = lrelu(sl_i + srmax) (monotonicity), srmax computed in prologue.
// Z via MFMA with all-ones B (row-sums land in C-fragment layout -> no
// shuffles anywhere). sr prefetched in registers; LDS offsets hoisted.
// Grid (16 bh, 32 it) x 256 thr — bh fastest => same-slice blocks share XCD L2.
__global__ __launch_bounds__(256) void k_attn(const ushort_t* __restrict__ gThi,
                                              const ushort_t* __restrict__ gTlo,
                                              const float* __restrict__ sl,
                                              const float* __restrict__ sr,
                                              float* __restrict__ out) {
  __shared__ ushort_t ghi[2][64 * 64];
  __shared__ ushort_t glo[2][64 * 64];
  __shared__ float wred[4];
  const int tid = threadIdx.x;
  const int lane = tid & 63;
  const int wave = tid >> 6;
  const int bh = blockIdx.x;
  const int b = bh >> 3, h = bh & 7;
  const int i0 = blockIdx.y * 64 + wave * 16;
  const int row_l = lane & 15;
  const int kg = lane >> 4;
  const int sd = tid >> 2;
  const int sj = (tid & 3) * 16;

  // prologue: srmax for this bh
  float mx = -1e30f;
  for (int q = tid; q < N_; q += 256) mx = fmaxf(mx, sr[bh * N_ + q]);
#pragma unroll
  for (int off = 32; off > 0; off >>= 1) mx = fmaxf(mx, __shfl_xor(mx, off, 64));
  if (lane == 0) wred[wave] = mx;
  __syncthreads();
  mx = fmaxf(fmaxf(wred[0], wred[1]), fmaxf(wred[2], wred[3]));

  const float sli = sl[bh * N_ + i0 + row_l];
  const float pre = sli + mx;
  const float Mi = fmaxf(pre, SLOPE * pre);  // exact row max of e
  const float negML2 = -Mi * LOG2E;

  // hoisted LDS read offsets (compile-time unrolled -> registers)
  int ridx[4][2];
#pragma unroll
  for (int gg = 0; gg < 4; ++gg) {
    const int d = gg * 16 + row_l;
#pragma unroll
    for (int kk = 0; kk < 2; ++kk) {
      const int j0r = kk * 32 + kg * 8;
      ridx[gg][kk] = d * 64 + (j0r ^ ((d & 7) << 3));
    }
  }
  const short8 ones = {0x3F80, 0x3F80, 0x3F80, 0x3F80,
                       0x3F80, 0x3F80, 0x3F80, 0x3F80};

  const ushort_t* gH = gThi + ((size_t)bh * 64 + sd) * N_ + sj;
  const ushort_t* gL = gTlo + ((size_t)bh * 64 + sd) * N_ + sj;
  const float* srp0 = sr + bh * N_ + kg * 8;        // kk=0 j-base
  const float* srp1 = sr + bh * N_ + 32 + kg * 8;   // kk=1 j-base

  float m_unused = 0.f;
  (void)m_unused;
  f32x4 O[4] = {};
  f32x4 Zacc = {};
  short8 sh0, sh1, sv0, sv1;
  float4 cs0a, cs0b, cs1a, cs1b;  // current sr (kk0:8, kk1:8)
  float4 ps0a, ps0b, ps1a, ps1b;  // prefetch

#define ALOAD(jb)                                                           \
  {                                                                         \
    sh0 = *(const short8*)&gH[jb];                                          \
    sh1 = *(const short8*)&gH[(jb) + 8];                                    \
    sv0 = *(const short8*)&gL[jb];                                          \
    sv1 = *(const short8*)&gL[(jb) + 8];                                    \
  }
#define SRLOAD(jb, a0, b0, a1, b1)                                          \
  {                                                                         \
    a0 = *(const float4*)&srp0[jb];                                         \
    b0 = *(const float4*)&srp0[(jb) + 4];                                   \
    a1 = *(const float4*)&srp1[jb];                                         \
    b1 = *(const float4*)&srp1[(jb) + 4];                                   \
  }
#define AWRITE(buf)                                                         \
  {                                                                         \
    const int base_ = sd * 64;                                              \
    const int sw_ = (sd & 7) << 3;                                          \
    *(short8*)&ghi[buf][base_ + (sj ^ sw_)] = sh0;                          \
    *(short8*)&ghi[buf][base_ + ((sj + 8) ^ sw_)] = sh1;                    \
    *(short8*)&glo[buf][base_ + (sj ^ sw_)] = sv0;                          \
    *(short8*)&glo[buf][base_ + ((sj + 8) ^ sw_)] = sv1;                    \
  }

  ALOAD(0);
  AWRITE(0);
  SRLOAD(0, cs0a, cs0b, cs1a, cs1b);
  __syncthreads();
  int cur = 0;
  for (int t = 0; t < 32; ++t) {
    if (t < 31) {
      ALOAD((t + 1) * 64);
      SRLOAD((t + 1) * 64, ps0a, ps0b, ps1a, ps1b);
    }
    // P = exp(lrelu(sli + sr_j) - Mi), bf16
    short8 a[2];
    {
      const float s0[8] = {cs0a.x, cs0a.y, cs0a.z, cs0a.w,
                           cs0b.x, cs0b.y, cs0b.z, cs0b.w};
      const float s1[8] = {cs1a.x, cs1a.y, cs1a.z, cs1a.w,
                           cs1b.x, cs1b.y, cs1b.z, cs1b.w};
#pragma unroll
      for (int u = 0; u < 8; ++u) {
        const float x0 = sli + s0[u];
        const float e0 = fmaxf(x0, SLOPE * x0);
        a[0][u] = (short)bf16_rne(exp2f(fmaf(e0, LOG2E, negML2)));
        const float x1 = sli + s1[u];
        const float e1 = fmaxf(x1, SLOPE * x1);
        a[1][u] = (short)bf16_rne(exp2f(fmaf(e1, LOG2E, negML2)));
      }
    }
    // Z row-sums via MFMA (ones B)
    Zacc = __builtin_amdgcn_mfma_f32_16x16x32_bf16(a[0], ones, Zacc, 0, 0, 0);
    Zacc = __builtin_amdgcn_mfma_f32_16x16x32_bf16(a[1], ones, Zacc, 0, 0, 0);
    // PV
#pragma unroll
    for (int gg = 0; gg < 4; ++gg)
#pragma unroll
      for (int kk = 0; kk < 2; ++kk) {
        const short8 b_h = *(const short8*)&ghi[cur][ridx[gg][kk]];
        const short8 b_l = *(const short8*)&glo[cur][ridx[gg][kk]];
        O[gg] = __builtin_amdgcn_mfma_f32_16x16x32_bf16(a[kk], b_h, O[gg], 0, 0, 0);
        O[gg] = __builtin_amdgcn_mfma_f32_16x16x32_bf16(a[kk], b_l, O[gg], 0, 0, 0);
      }
    if (t < 31) {
      AWRITE(cur ^ 1);
      cs0a = ps0a; cs0b = ps0b; cs1a = ps1a; cs1b = ps1b;
    }
    __syncthreads();
    cur ^= 1;
  }
#undef ALOAD
#undef SRLOAD
#undef AWRITE
  // epilogue: O / Z (Zacc shares the C-fragment row layout — no shuffles)
#pragma unroll
  for (int gg = 0; gg < 4; ++gg)
#pragma unroll
    for (int rr = 0; rr < 4; ++rr) {
      const int row = i0 + kg * 4 + rr;
      const int col = h * DH + gg * 16 + row_l;
      out[(b * N_ + row) * HD + col] = O[gg][rr] / Zacc[rr];
    }
}

extern "C" void kernel_launch(void* const* d_in, const int* in_sizes, int n_in,
                              void* d_out, int out_size, void* d_ws, size_t ws_size,
                              hipStream_t stream) {
  const float* f = (const float*)d_in[0];
  // d_in[1] = adj_mat (all ones, unused by reference math)
  const float* W = (const float*)d_in[2];
  const float* aw = (const float*)d_in[3];
  float* out = (float*)d_out;

  ushort_t* gThi = (ushort_t*)d_ws;          // [16 bh][64 d][2048 n] bf16 hi
  ushort_t* gTlo = gThi + 16 * 64 * N_;      // lo
  float* sl = (float*)(gTlo + 16 * 64 * N_); // [bh][n]
  float* sr = sl + B_ * N_ * H_;

  hipLaunchKernelGGL(k_gemm_fused, dim3((B_ * N_) / 128, HD / 64), dim3(512), 0, stream,
                     f, W, aw, gThi, gTlo, sl, sr);
  hipLaunchKernelGGL(k_attn, dim3(B_ * H_, N_ / 64), dim3(256), 0, stream,
                     gThi, gTlo, sl, sr, out);
}